// Round 5
// baseline (4140.317 us; speedup 1.0000x reference)
//
#include <hip/hip_runtime.h>
#include <hip/hip_bf16.h>
#include <math.h>

typedef __hip_bfloat16 bf16;

// Problem constants
#define Bsz 4
#define Lseq 2048
#define DM 256       // d_model == per-head D (informer quirk: head dim = d_model)
#define HH 8
#define HD 2048      // H * DM
#define DFF 1024
#define SK 40
#define NTOP 5
#define MROWS 8192   // B * L

// ---------------------------------------------------------------------------
// Static device scratch (no d_ws dependence). __align__(256) is REQUIRED:
// these are cast to float4* (round-3 abort root cause: default 4B alignment).
// Every array fully rewritten before read each call (graph-replay safe).
// NOTE: inputs are FP32 (reference is jnp.float32; round-4 NaN came from
// misreading fp32 buffers as bf16).
__device__ __align__(256) float g_X  [MROWS * DM];    //  8 MB activations
__device__ __align__(256) float g_TMP[MROWS * DM];    //  8 MB residual accum
__device__ __align__(256) float g_QH [MROWS * DM];    //  8 MB per-head Q
__device__ __align__(256) float g_KH [MROWS * DM];    //  8 MB per-head K
__device__ __align__(256) float g_VH [MROWS * DM];    //  8 MB per-head V
__device__ __align__(256) bf16  g_HF [MROWS * DFF];   // 16 MB FFN hidden (bf16)
__device__ __align__(256) float g_MB [MROWS];         // sparsity measure M
__device__ __align__(256) float g_CTX[Bsz * NTOP * DM];
__device__ __align__(256) int   g_MTOP[Bsz * NTOP];

__device__ __forceinline__ float ld(const float* p, size_t i) { return p[i]; }
__device__ __forceinline__ float ld(const bf16* p, size_t i) { return __bfloat162float(p[i]); }
__device__ __forceinline__ void st(float* p, size_t i, float v) { p[i] = v; }
__device__ __forceinline__ void st(bf16* p, size_t i, float v) { p[i] = __float2bfloat16(v); }

// ---------------------------------------------------------------------------
// Tiled GEMM body: C[.,N] = op(A[.,K] @ W[.,N] + bias (+res))
// A fp32/bf16 row stride K; W/bias fp32 row stride ldw; C fp32/bf16 stride ldc.
// 64x64 tile, BK=16, 4x4 per thread, 256 threads.
template<typename TA, typename TC, bool GELU, bool RES>
__device__ __forceinline__ void gemm_body(
    const TA* __restrict__ A, const float* __restrict__ W,
    const float* __restrict__ bias, const float* __restrict__ res,
    TC* __restrict__ C, int K, int ldw, int ldc, int bx, int by)
{
    const int BM = 64, BN = 64, BK = 16;
    __shared__ __align__(16) float As[BK][BM + 4];
    __shared__ __align__(16) float Bs[BK][BN];
    int tid = threadIdx.x;
    int tx = tid & 15, ty = tid >> 4;
    int row0 = by * BM, col0 = bx * BN;
    float acc[4][4] = {};
    for (int k0 = 0; k0 < K; k0 += BK) {
        #pragma unroll
        for (int i = 0; i < 4; i++) {
            int idx = tid + i * 256;
            int r = idx >> 4, c = idx & 15;
            As[c][r] = ld(A, (size_t)(row0 + r) * K + k0 + c);
        }
        #pragma unroll
        for (int i = 0; i < 4; i++) {
            int idx = tid + i * 256;
            int r = idx >> 6, c = idx & 63;
            Bs[r][c] = W[(size_t)(k0 + r) * ldw + col0 + c];
        }
        __syncthreads();
        #pragma unroll
        for (int kk = 0; kk < BK; kk++) {
            float a[4], b[4];
            #pragma unroll
            for (int i = 0; i < 4; i++) a[i] = As[kk][ty * 4 + i];
            #pragma unroll
            for (int j = 0; j < 4; j++) b[j] = Bs[kk][tx * 4 + j];
            #pragma unroll
            for (int i = 0; i < 4; i++)
                #pragma unroll
                for (int j = 0; j < 4; j++) acc[i][j] += a[i] * b[j];
        }
        __syncthreads();
    }
    #pragma unroll
    for (int i = 0; i < 4; i++) {
        int r = row0 + ty * 4 + i;
        #pragma unroll
        for (int j = 0; j < 4; j++) {
            int c = col0 + tx * 4 + j;
            float v = acc[i][j] + bias[c];
            if (RES) v += res[(size_t)r * ldc + c];
            if (GELU) v = 0.5f * v * (1.0f + erff(v * 0.70710678118654752440f));
            st(C, (size_t)r * ldc + c, v);
        }
    }
}

// ---- GEMM wrapper kernels ----
// embedding: g_X = x_enc[8192,32] @ emb_W[32,256] + emb_b
__global__ __launch_bounds__(256) void emb_gemm(const float* __restrict__ A,
                                                const float* __restrict__ W,
                                                const float* __restrict__ bias) {
    gemm_body<float, float, false, false>(A, W, bias, nullptr, g_X, 32, DM, DM,
                                          blockIdx.x, blockIdx.y);
}

// Q/K/V for one head: blockIdx.z selects target. W*/b* pre-offset (layer,head).
__global__ __launch_bounds__(256) void qkv_gemm(
    const float* __restrict__ Wq, const float* __restrict__ Wk, const float* __restrict__ Wv,
    const float* __restrict__ bq, const float* __restrict__ bk, const float* __restrict__ bv)
{
    int z = blockIdx.z;
    const float* W  = (z == 0) ? Wq : (z == 1) ? Wk : Wv;
    const float* bb = (z == 0) ? bq : (z == 1) ? bk : bv;
    float* C = (z == 0) ? g_QH : (z == 1) ? g_KH : g_VH;
    gemm_body<float, float, false, false>(g_X, W, bb, nullptr, C, DM, HD, DM,
                                          blockIdx.x, blockIdx.y);
}

// FFN1: g_HF(bf16) = gelu(g_X @ c1W + c1b)
__global__ __launch_bounds__(256) void ffn1_gemm(const float* __restrict__ W,
                                                 const float* __restrict__ bias) {
    gemm_body<float, bf16, true, false>(g_X, W, bias, nullptr, g_HF, DM, DFF, DFF,
                                        blockIdx.x, blockIdx.y);
}

// FFN2: g_TMP = g_HF @ c2W + c2b + g_X
__global__ __launch_bounds__(256) void ffn2_gemm(const float* __restrict__ W,
                                                 const float* __restrict__ bias) {
    gemm_body<bf16, float, false, true>(g_HF, W, bias, g_X, g_TMP, DFF, DM, DM,
                                        blockIdx.x, blockIdx.y);
}

// ---------------------------------------------------------------------------
// Sampled scores + sparsity measure M for ONE head. One wave per (b,l).
__global__ __launch_bounds__(256) void sampm_kernel(const int* __restrict__ idx)
{
    int wid = blockIdx.x * 4 + (threadIdx.x >> 6);   // b*L + l
    if (wid >= MROWS) return;
    int lane = threadIdx.x & 63;
    int l = wid & (Lseq - 1);
    int b = wid >> 11;
    const float4* qrow = (const float4*)(g_QH + (size_t)wid * DM);
    float4 qf = qrow[lane];
    float maxv = -INFINITY, sumv = 0.f;
    for (int u = 0; u < SK; u++) {
        int s = idx[l * SK + u] & (Lseq - 1);        // clamp: semantic no-op
        const float4* krow = (const float4*)(g_KH + ((size_t)(b * Lseq + s)) * DM);
        float4 kf = krow[lane];
        float p = qf.x * kf.x + qf.y * kf.y + qf.z * kf.z + qf.w * kf.w;
        #pragma unroll
        for (int off = 32; off > 0; off >>= 1) p += __shfl_down(p, off, 64);
        if (lane == 0) { maxv = fmaxf(maxv, p); sumv += p; }
    }
    if (lane == 0) g_MB[wid] = maxv - sumv * (1.0f / (float)Lseq);
}

// ---------------------------------------------------------------------------
// Top-5 per b via 5 masked argmax passes (ties -> lower index, like lax.top_k)
__global__ __launch_bounds__(256) void topk_kernel(int dummy)
{
    (void)dummy;
    __shared__ float vals[Lseq];
    __shared__ float rv[256];
    __shared__ int ri[256];
    int b = blockIdx.x, tid = threadIdx.x;
    for (int i = tid; i < Lseq; i += 256) vals[i] = g_MB[b * Lseq + i];
    __syncthreads();
    for (int t = 0; t < NTOP; t++) {
        float bv = -INFINITY; int bi = Lseq - 1;
        for (int i = tid; i < Lseq; i += 256) {
            float v = vals[i];
            if (v > bv || (v == bv && i < bi)) { bv = v; bi = i; }
        }
        rv[tid] = bv; ri[tid] = bi;
        __syncthreads();
        for (int s = 128; s > 0; s >>= 1) {
            if (tid < s) {
                float ov = rv[tid + s]; int oi = ri[tid + s];
                if (ov > rv[tid] || (ov == rv[tid] && oi < ri[tid])) { rv[tid] = ov; ri[tid] = oi; }
            }
            __syncthreads();
        }
        if (tid == 0) { g_MTOP[b * NTOP + t] = ri[0]; vals[ri[0] & (Lseq - 1)] = -INFINITY; }
        __syncthreads();
    }
}

// ---------------------------------------------------------------------------
// Attention for ONE top query: block = (b*NTOP + t). LDS 10 KB.
__global__ __launch_bounds__(256) void attn_kernel(int dummy)
{
    (void)dummy;
    __shared__ __align__(16) float qs[DM];
    __shared__ __align__(16) float sc[Lseq];
    __shared__ float red[256];
    int bt = blockIdx.x;               // b*NTOP + t
    int b = bt / NTOP;
    int tid = threadIdx.x;
    int l = g_MTOP[bt] & (Lseq - 1);
    qs[tid] = g_QH[((size_t)(b * Lseq + l)) * DM + tid];
    __syncthreads();
    // scores: thread tid covers keys j = jj*256+tid
    for (int jj = 0; jj < Lseq / 256; jj++) {
        int j = jj * 256 + tid;
        const float4* krow = (const float4*)(g_KH + ((size_t)(b * Lseq + j)) * DM);
        float acc = 0.f;
        for (int d4 = 0; d4 < DM / 4; d4++) {
            float4 kf = krow[d4];
            float4 qf = ((const float4*)qs)[d4];
            acc += qf.x * kf.x + qf.y * kf.y + qf.z * kf.z + qf.w * kf.w;
        }
        sc[j] = acc;
    }
    __syncthreads();
    // softmax over sc[0..Lseq)
    float m = -INFINITY;
    for (int i = tid; i < Lseq; i += 256) m = fmaxf(m, sc[i]);
    red[tid] = m; __syncthreads();
    for (int s = 128; s > 0; s >>= 1) { if (tid < s) red[tid] = fmaxf(red[tid], red[tid + s]); __syncthreads(); }
    m = red[0]; __syncthreads();
    float sum = 0.f;
    for (int i = tid; i < Lseq; i += 256) { float e = expf(sc[i] - m); sc[i] = e; sum += e; }
    red[tid] = sum; __syncthreads();
    for (int s = 128; s > 0; s >>= 1) { if (tid < s) red[tid] += red[tid + s]; __syncthreads(); }
    float inv = 1.0f / red[0]; __syncthreads();
    for (int i = tid; i < Lseq; i += 256) sc[i] *= inv;
    __syncthreads();
    // ctx: thread tid = output dim d (coalesced V reads across threads)
    float accv = 0.f;
    const float* vbase = g_VH + (size_t)b * Lseq * DM + tid;
    for (int j = 0; j < Lseq; j++) accv += sc[j] * vbase[(size_t)j * DM];
    g_CTX[(size_t)bt * DM + tid] = accv;
}

// ---------------------------------------------------------------------------
// g_TMP = g_X + bo (broadcast)
__global__ __launch_bounds__(256) void add_bias_kernel(const float* __restrict__ bo)
{
    int i = blockIdx.x * 256 + threadIdx.x;
    g_TMP[i] = g_X[i] + bo[i & (DM - 1)];
}

// g_TMP[row(b,t)] += g_CTX[b,t] @ Wo_h  (Wo_h = head-h row block [DM,DM])
__global__ __launch_bounds__(256) void scatter_kernel(const float* __restrict__ Wo_h)
{
    __shared__ float cs[DM];
    int bt = blockIdx.x;              // b*NTOP + t
    int b = bt / NTOP;
    int tid = threadIdx.x;
    cs[tid] = g_CTX[(size_t)bt * DM + tid];
    __syncthreads();
    int row = g_MTOP[bt] & (Lseq - 1);
    float acc = 0.f;
    const float* w = Wo_h + tid;
    for (int d = 0; d < DM; d++) acc += cs[d] * w[(size_t)d * DM];
    atomicAdd(&g_TMP[((size_t)(b * Lseq) + row) * DM + tid], acc);
}

// ---------------------------------------------------------------------------
// LayerNorm g_TMP -> g_X, one wave per row of 256
__global__ __launch_bounds__(256) void ln_kernel(const float* __restrict__ g,
                                                 const float* __restrict__ bb)
{
    int wid = blockIdx.x * 4 + (threadIdx.x >> 6);
    if (wid >= MROWS) return;
    int lane = threadIdx.x & 63;
    const float4* row = (const float4*)(g_TMP + (size_t)wid * DM);
    float4 v = row[lane];
    float s = v.x + v.y + v.z + v.w;
    #pragma unroll
    for (int off = 32; off > 0; off >>= 1) s += __shfl_down(s, off, 64);
    s = __shfl(s, 0, 64);
    float mean = s * (1.f / DM);
    float4 d = {v.x - mean, v.y - mean, v.z - mean, v.w - mean};
    float q = d.x * d.x + d.y * d.y + d.z * d.z + d.w * d.w;
    #pragma unroll
    for (int off = 32; off > 0; off >>= 1) q += __shfl_down(q, off, 64);
    q = __shfl(q, 0, 64);
    float inv = rsqrtf(q * (1.f / DM) + 1e-5f);
    int c = lane * 4;
    float4 o;
    o.x = d.x * inv * g[c + 0] + bb[c + 0];
    o.y = d.y * inv * g[c + 1] + bb[c + 1];
    o.z = d.z * inv * g[c + 2] + bb[c + 2];
    o.w = d.w * inv * g[c + 3] + bb[c + 3];
    ((float4*)(g_X + (size_t)wid * DM))[lane] = o;
}

// ---------------------------------------------------------------------------
// Final: LN(nf) on row L-1 of each batch, dot with proj_W, + proj_b -> out[b]
__global__ __launch_bounds__(256) void final_kernel(
    const float* __restrict__ g, const float* __restrict__ bb,
    const float* __restrict__ pw, const float* __restrict__ pb,
    float* __restrict__ out)
{
    __shared__ float red[256];
    int b = blockIdx.x, tid = threadIdx.x;
    const float* row = g_X + ((size_t)(b * Lseq + Lseq - 1)) * DM;
    float v = row[tid];
    red[tid] = v; __syncthreads();
    for (int s = 128; s > 0; s >>= 1) { if (tid < s) red[tid] += red[tid + s]; __syncthreads(); }
    float mean = red[0] * (1.f / DM); __syncthreads();
    float d = v - mean;
    red[tid] = d * d; __syncthreads();
    for (int s = 128; s > 0; s >>= 1) { if (tid < s) red[tid] += red[tid + s]; __syncthreads(); }
    float var = red[0] * (1.f / DM); __syncthreads();
    float xn = d * rsqrtf(var + 1e-5f) * g[tid] + bb[tid];
    red[tid] = xn * pw[tid]; __syncthreads();
    for (int s = 128; s > 0; s >>= 1) { if (tid < s) red[tid] += red[tid + s]; __syncthreads(); }
    if (tid == 0) out[b] = red[0] + pb[0];
}

// ---------------------------------------------------------------------------
extern "C" void kernel_launch(void* const* d_in, const int* in_sizes, int n_in,
                              void* d_out, int out_size, void* d_ws, size_t ws_size,
                              hipStream_t stream)
{
    const float* x_enc = (const float*)d_in[0];
    const int*   isamp = (const int*)d_in[1];
    const float* emb_W = (const float*)d_in[2];
    const float* emb_b = (const float*)d_in[3];
    const float* Wq = (const float*)d_in[4];
    const float* bq = (const float*)d_in[5];
    const float* Wk = (const float*)d_in[6];
    const float* bk = (const float*)d_in[7];
    const float* Wv = (const float*)d_in[8];
    const float* bv = (const float*)d_in[9];
    const float* Wo = (const float*)d_in[10];
    const float* bo = (const float*)d_in[11];
    const float* c1W = (const float*)d_in[12];
    const float* c1b = (const float*)d_in[13];
    const float* c2W = (const float*)d_in[14];
    const float* c2b = (const float*)d_in[15];
    const float* ln1g = (const float*)d_in[16];
    const float* ln1b = (const float*)d_in[17];
    const float* ln2g = (const float*)d_in[18];
    const float* ln2b = (const float*)d_in[19];
    const float* nfg  = (const float*)d_in[20];
    const float* nfb  = (const float*)d_in[21];
    const float* projW = (const float*)d_in[22];
    const float* projb = (const float*)d_in[23];
    (void)d_ws; (void)ws_size; (void)in_sizes; (void)n_in; (void)out_size;

    dim3 blk(256);
    emb_gemm<<<dim3(DM / 64, MROWS / 64), blk, 0, stream>>>(x_enc, emb_W, emb_b);

    for (int l = 0; l < 2; l++) {
        const float* Wq_l = Wq + (size_t)l * DM * HD;
        const float* Wk_l = Wk + (size_t)l * DM * HD;
        const float* Wv_l = Wv + (size_t)l * DM * HD;
        const float* Wo_l = Wo + (size_t)l * HD * DM;

        add_bias_kernel<<<dim3(MROWS), blk, 0, stream>>>(bo + l * DM);

        for (int h = 0; h < HH; h++) {
            qkv_gemm<<<dim3(DM / 64, MROWS / 64, 3), blk, 0, stream>>>(
                Wq_l + h * DM, Wk_l + h * DM, Wv_l + h * DM,
                bq + l * HD + h * DM, bk + l * HD + h * DM, bv + l * HD + h * DM);
            sampm_kernel<<<dim3(MROWS / 4), blk, 0, stream>>>(isamp);
            topk_kernel<<<dim3(Bsz), blk, 0, stream>>>(0);
            attn_kernel<<<dim3(Bsz * NTOP), blk, 0, stream>>>(0);
            scatter_kernel<<<dim3(Bsz * NTOP), blk, 0, stream>>>(
                Wo_l + (size_t)h * DM * DM);
        }
        ln_kernel<<<dim3(MROWS / 4), blk, 0, stream>>>(ln1g + l * DM, ln1b + l * DM);

        ffn1_gemm<<<dim3(DFF / 64, MROWS / 64), blk, 0, stream>>>(
            c1W + (size_t)l * DM * DFF, c1b + l * DFF);
        ffn2_gemm<<<dim3(DM / 64, MROWS / 64), blk, 0, stream>>>(
            c2W + (size_t)l * DFF * DM, c2b + l * DM);
        ln_kernel<<<dim3(MROWS / 4), blk, 0, stream>>>(ln2g + l * DM, ln2b + l * DM);
    }

    final_kernel<<<dim3(Bsz), blk, 0, stream>>>(nfg, nfb, projW, projb, (float*)d_out);
}

// Round 6
// 1830.718 us; speedup vs baseline: 2.2616x; 2.2616x over previous
//
#include <hip/hip_runtime.h>
#include <hip/hip_bf16.h>
#include <math.h>

typedef __hip_bfloat16 bf16;

// Problem constants
#define Bsz 4
#define Lseq 2048
#define DM 256       // d_model == per-head D (informer quirk: head dim = d_model)
#define HH 8
#define HD 2048      // H * DM
#define DFF 1024
#define SK 40
#define NTOP 5
#define MROWS 8192   // B * L
#define NBT (Bsz * HH * NTOP)   // 160 (b,h,topquery) triples
#define NCHUNK 8                // key chunks of 256

// ---------------------------------------------------------------------------
// Static device scratch (no d_ws dependence). __align__(256) REQUIRED for the
// float4* casts. Every array fully rewritten before read each call.
// Inputs are FP32 (reference is jnp.float32).
__device__ __align__(256) float g_X  [MROWS * DM];    //   8 MB activations
__device__ __align__(256) float g_TMP[MROWS * DM];    //   8 MB residual accum
__device__ __align__(256) float g_Q  [MROWS * HD];    //  64 MB all-head Q
__device__ __align__(256) float g_K  [MROWS * HD];    //  64 MB all-head K
__device__ __align__(256) float g_V  [MROWS * HD];    //  64 MB all-head V
__device__ __align__(256) bf16  g_HF [MROWS * DFF];   //  16 MB FFN hidden (bf16)
__device__ __align__(256) float g_MB [Bsz * HH * Lseq];        // sparsity measure
__device__ __align__(256) float g_SC [NBT * Lseq];             // scores/probs 1.25 MB
__device__ __align__(256) float g_CTXP[NBT * NCHUNK * DM];     // partial ctx 1.25 MB
__device__ __align__(256) int   g_MTOP[NBT];

__device__ __forceinline__ float ld(const float* p, size_t i) { return p[i]; }
__device__ __forceinline__ float ld(const bf16* p, size_t i) { return __bfloat162float(p[i]); }
__device__ __forceinline__ void st(float* p, size_t i, float v) { p[i] = v; }
__device__ __forceinline__ void st(bf16* p, size_t i, float v) { p[i] = __float2bfloat16(v); }

// ---------------------------------------------------------------------------
// Tiled GEMM body: C[.,N] = op(A[.,K] @ W[.,N] + bias (+res))
// 64x64 tile, BK=16, 4x4 per thread, 256 threads.
template<typename TA, typename TC, bool GELU, bool RES>
__device__ __forceinline__ void gemm_body(
    const TA* __restrict__ A, const float* __restrict__ W,
    const float* __restrict__ bias, const float* __restrict__ res,
    TC* __restrict__ C, int K, int ldw, int ldc, int bx, int by)
{
    const int BM = 64, BN = 64, BK = 16;
    __shared__ __align__(16) float As[BK][BM + 4];
    __shared__ __align__(16) float Bs[BK][BN];
    int tid = threadIdx.x;
    int tx = tid & 15, ty = tid >> 4;
    int row0 = by * BM, col0 = bx * BN;
    float acc[4][4] = {};
    for (int k0 = 0; k0 < K; k0 += BK) {
        #pragma unroll
        for (int i = 0; i < 4; i++) {
            int idx = tid + i * 256;
            int r = idx >> 4, c = idx & 15;
            As[c][r] = ld(A, (size_t)(row0 + r) * K + k0 + c);
        }
        #pragma unroll
        for (int i = 0; i < 4; i++) {
            int idx = tid + i * 256;
            int r = idx >> 6, c = idx & 63;
            Bs[r][c] = W[(size_t)(k0 + r) * ldw + col0 + c];
        }
        __syncthreads();
        #pragma unroll
        for (int kk = 0; kk < BK; kk++) {
            float a[4], b[4];
            #pragma unroll
            for (int i = 0; i < 4; i++) a[i] = As[kk][ty * 4 + i];
            #pragma unroll
            for (int j = 0; j < 4; j++) b[j] = Bs[kk][tx * 4 + j];
            #pragma unroll
            for (int i = 0; i < 4; i++)
                #pragma unroll
                for (int j = 0; j < 4; j++) acc[i][j] += a[i] * b[j];
        }
        __syncthreads();
    }
    #pragma unroll
    for (int i = 0; i < 4; i++) {
        int r = row0 + ty * 4 + i;
        #pragma unroll
        for (int j = 0; j < 4; j++) {
            int c = col0 + tx * 4 + j;
            float v = acc[i][j] + bias[c];
            if (RES) v += res[(size_t)r * ldc + c];
            if (GELU) v = 0.5f * v * (1.0f + erff(v * 0.70710678118654752440f));
            st(C, (size_t)r * ldc + c, v);
        }
    }
}

// ---- GEMM wrapper kernels ----
__global__ __launch_bounds__(256) void emb_gemm(const float* __restrict__ A,
                                                const float* __restrict__ W,
                                                const float* __restrict__ bias) {
    gemm_body<float, float, false, false>(A, W, bias, nullptr, g_X, 32, DM, DM,
                                          blockIdx.x, blockIdx.y);
}

// All-head Q/K/V per layer: grid (HD/64, MROWS/64, 3); z selects target.
__global__ __launch_bounds__(256) void qkv_gemm(
    const float* __restrict__ Wq, const float* __restrict__ Wk, const float* __restrict__ Wv,
    const float* __restrict__ bq, const float* __restrict__ bk, const float* __restrict__ bv)
{
    int z = blockIdx.z;
    const float* W  = (z == 0) ? Wq : (z == 1) ? Wk : Wv;
    const float* bb = (z == 0) ? bq : (z == 1) ? bk : bv;
    float* C = (z == 0) ? g_Q : (z == 1) ? g_K : g_V;
    gemm_body<float, float, false, false>(g_X, W, bb, nullptr, C, DM, HD, HD,
                                          blockIdx.x, blockIdx.y);
}

__global__ __launch_bounds__(256) void ffn1_gemm(const float* __restrict__ W,
                                                 const float* __restrict__ bias) {
    gemm_body<float, bf16, true, false>(g_X, W, bias, nullptr, g_HF, DM, DFF, DFF,
                                        blockIdx.x, blockIdx.y);
}

__global__ __launch_bounds__(256) void ffn2_gemm(const float* __restrict__ W,
                                                 const float* __restrict__ bias) {
    gemm_body<bf16, float, false, true>(g_HF, W, bias, g_X, g_TMP, DFF, DM, DM,
                                        blockIdx.x, blockIdx.y);
}

// ---------------------------------------------------------------------------
// Sampled scores + sparsity measure M, ALL heads. One wave per (b,h,l).
// Waves: B*H*L = 65536; grid 16384 blocks x 4 waves.
__global__ __launch_bounds__(256) void sampm_kernel(const int* __restrict__ idx)
{
    int wid = blockIdx.x * 4 + (threadIdx.x >> 6);   // (b*H+h)*L + l
    int lane = threadIdx.x & 63;
    int l = wid & (Lseq - 1);
    int bh = wid >> 11;
    int b = bh >> 3, h = bh & 7;
    const float4* qrow = (const float4*)(g_Q + ((size_t)(b * Lseq + l)) * HD + h * DM);
    float4 qf = qrow[lane];
    float maxv = -INFINITY, sumv = 0.f;
    for (int u = 0; u < SK; u++) {
        int s = idx[l * SK + u] & (Lseq - 1);        // clamp: semantic no-op
        const float4* krow = (const float4*)(g_K + ((size_t)(b * Lseq + s)) * HD + h * DM);
        float4 kf = krow[lane];
        float p = qf.x * kf.x + qf.y * kf.y + qf.z * kf.z + qf.w * kf.w;
        #pragma unroll
        for (int off = 32; off > 0; off >>= 1) p += __shfl_down(p, off, 64);
        if (lane == 0) { maxv = fmaxf(maxv, p); sumv += p; }
    }
    if (lane == 0) g_MB[wid] = maxv - sumv * (1.0f / (float)Lseq);
}

// ---------------------------------------------------------------------------
// Top-5 per (b,h): grid 32. 5 masked argmax passes (ties -> lower index).
__global__ __launch_bounds__(256) void topk_kernel(int dummy)
{
    (void)dummy;
    __shared__ float vals[Lseq];
    __shared__ float rv[256];
    __shared__ int ri[256];
    int bh = blockIdx.x, tid = threadIdx.x;
    for (int i = tid; i < Lseq; i += 256) vals[i] = g_MB[bh * Lseq + i];
    __syncthreads();
    for (int t = 0; t < NTOP; t++) {
        float bv = -INFINITY; int bi = Lseq - 1;
        for (int i = tid; i < Lseq; i += 256) {
            float v = vals[i];
            if (v > bv || (v == bv && i < bi)) { bv = v; bi = i; }
        }
        rv[tid] = bv; ri[tid] = bi;
        __syncthreads();
        for (int s = 128; s > 0; s >>= 1) {
            if (tid < s) {
                float ov = rv[tid + s]; int oi = ri[tid + s];
                if (ov > rv[tid] || (ov == rv[tid] && oi < ri[tid])) { rv[tid] = ov; ri[tid] = oi; }
            }
            __syncthreads();
        }
        if (tid == 0) { g_MTOP[bh * NTOP + t] = ri[0]; vals[ri[0] & (Lseq - 1)] = -INFINITY; }
        __syncthreads();
    }
}

// ---------------------------------------------------------------------------
// Scores for top queries: grid (NBT=160, NCHUNK=8). Thread = one key.
__global__ __launch_bounds__(256) void attn_scores(int dummy)
{
    (void)dummy;
    __shared__ __align__(16) float qs[DM];
    int bt = blockIdx.x, chunk = blockIdx.y, tid = threadIdx.x;
    int bh = bt / NTOP;
    int b = bh >> 3, h = bh & 7;
    int l = g_MTOP[bt] & (Lseq - 1);
    qs[tid] = g_Q[((size_t)(b * Lseq + l)) * HD + h * DM + tid];
    __syncthreads();
    int j = chunk * 256 + tid;
    const float4* krow = (const float4*)(g_K + ((size_t)(b * Lseq + j)) * HD + h * DM);
    float acc = 0.f;
    for (int d4 = 0; d4 < DM / 4; d4++) {
        float4 kf = krow[d4];
        float4 qf = ((const float4*)qs)[d4];
        acc += qf.x * kf.x + qf.y * kf.y + qf.z * kf.z + qf.w * kf.w;
    }
    g_SC[(size_t)bt * Lseq + j] = acc;
}

// Softmax in place over g_SC row: grid NBT=160.
__global__ __launch_bounds__(256) void attn_softmax(int dummy)
{
    (void)dummy;
    __shared__ float sc[Lseq];
    __shared__ float red[256];
    int bt = blockIdx.x, tid = threadIdx.x;
    for (int i = tid; i < Lseq; i += 256) sc[i] = g_SC[(size_t)bt * Lseq + i];
    __syncthreads();
    float m = -INFINITY;
    for (int i = tid; i < Lseq; i += 256) m = fmaxf(m, sc[i]);
    red[tid] = m; __syncthreads();
    for (int s = 128; s > 0; s >>= 1) { if (tid < s) red[tid] = fmaxf(red[tid], red[tid + s]); __syncthreads(); }
    m = red[0]; __syncthreads();
    float sum = 0.f;
    for (int i = tid; i < Lseq; i += 256) { float e = expf(sc[i] - m); sc[i] = e; sum += e; }
    red[tid] = sum; __syncthreads();
    for (int s = 128; s > 0; s >>= 1) { if (tid < s) red[tid] += red[tid + s]; __syncthreads(); }
    float inv = 1.0f / red[0]; __syncthreads();
    for (int i = tid; i < Lseq; i += 256) g_SC[(size_t)bt * Lseq + i] = sc[i] * inv;
}

// Partial ctx over one key chunk: grid (NBT=160, NCHUNK=8). Thread = dim.
__global__ __launch_bounds__(256) void attn_ctx(int dummy)
{
    (void)dummy;
    __shared__ float ps[256];
    int bt = blockIdx.x, chunk = blockIdx.y, tid = threadIdx.x;
    int bh = bt / NTOP;
    int b = bh >> 3, h = bh & 7;
    int j0 = chunk * 256;
    ps[tid] = g_SC[(size_t)bt * Lseq + j0 + tid];
    __syncthreads();
    float accv = 0.f;
    const float* vbase = g_V + ((size_t)(b * Lseq + j0)) * HD + h * DM + tid;
    for (int j = 0; j < 256; j++) accv += ps[j] * vbase[(size_t)j * HD];
    g_CTXP[((size_t)bt * NCHUNK + chunk) * DM + tid] = accv;
}

// ---------------------------------------------------------------------------
// g_TMP = g_X + bo (broadcast)
__global__ __launch_bounds__(256) void add_bias_kernel(const float* __restrict__ bo)
{
    int i = blockIdx.x * 256 + threadIdx.x;
    g_TMP[i] = g_X[i] + bo[i & (DM - 1)];
}

// Reduce ctx partials, project through Wo_h, scatter-add: grid NBT=160.
__global__ __launch_bounds__(256) void scatter_kernel(const float* __restrict__ Wo_l)
{
    __shared__ float cs[DM];
    int bt = blockIdx.x, tid = threadIdx.x;
    int bh = bt / NTOP;
    int b = bh >> 3, h = bh & 7;
    float s = 0.f;
    #pragma unroll
    for (int c = 0; c < NCHUNK; c++) s += g_CTXP[((size_t)bt * NCHUNK + c) * DM + tid];
    cs[tid] = s;
    __syncthreads();
    int row = g_MTOP[bt] & (Lseq - 1);
    float acc = 0.f;
    const float* w = Wo_l + (size_t)h * DM * DM + tid;   // element (h*DM+d, tid)
    for (int d = 0; d < DM; d++) acc += cs[d] * w[(size_t)d * DM];
    atomicAdd(&g_TMP[((size_t)(b * Lseq) + row) * DM + tid], acc);
}

// ---------------------------------------------------------------------------
// LayerNorm g_TMP -> g_X, one wave per row of 256
__global__ __launch_bounds__(256) void ln_kernel(const float* __restrict__ g,
                                                 const float* __restrict__ bb)
{
    int wid = blockIdx.x * 4 + (threadIdx.x >> 6);
    if (wid >= MROWS) return;
    int lane = threadIdx.x & 63;
    const float4* row = (const float4*)(g_TMP + (size_t)wid * DM);
    float4 v = row[lane];
    float s = v.x + v.y + v.z + v.w;
    #pragma unroll
    for (int off = 32; off > 0; off >>= 1) s += __shfl_down(s, off, 64);
    s = __shfl(s, 0, 64);
    float mean = s * (1.f / DM);
    float4 d = {v.x - mean, v.y - mean, v.z - mean, v.w - mean};
    float q = d.x * d.x + d.y * d.y + d.z * d.z + d.w * d.w;
    #pragma unroll
    for (int off = 32; off > 0; off >>= 1) q += __shfl_down(q, off, 64);
    q = __shfl(q, 0, 64);
    float inv = rsqrtf(q * (1.f / DM) + 1e-5f);
    int c = lane * 4;
    float4 o;
    o.x = d.x * inv * g[c + 0] + bb[c + 0];
    o.y = d.y * inv * g[c + 1] + bb[c + 1];
    o.z = d.z * inv * g[c + 2] + bb[c + 2];
    o.w = d.w * inv * g[c + 3] + bb[c + 3];
    ((float4*)(g_X + (size_t)wid * DM))[lane] = o;
}

// ---------------------------------------------------------------------------
// Final: LN(nf) on row L-1 of each batch, dot with proj_W, + proj_b -> out[b]
__global__ __launch_bounds__(256) void final_kernel(
    const float* __restrict__ g, const float* __restrict__ bb,
    const float* __restrict__ pw, const float* __restrict__ pb,
    float* __restrict__ out)
{
    __shared__ float red[256];
    int b = blockIdx.x, tid = threadIdx.x;
    const float* row = g_X + ((size_t)(b * Lseq + Lseq - 1)) * DM;
    float v = row[tid];
    red[tid] = v; __syncthreads();
    for (int s = 128; s > 0; s >>= 1) { if (tid < s) red[tid] += red[tid + s]; __syncthreads(); }
    float mean = red[0] * (1.f / DM); __syncthreads();
    float d = v - mean;
    red[tid] = d * d; __syncthreads();
    for (int s = 128; s > 0; s >>= 1) { if (tid < s) red[tid] += red[tid + s]; __syncthreads(); }
    float var = red[0] * (1.f / DM); __syncthreads();
    float xn = d * rsqrtf(var + 1e-5f) * g[tid] + bb[tid];
    red[tid] = xn * pw[tid]; __syncthreads();
    for (int s = 128; s > 0; s >>= 1) { if (tid < s) red[tid] += red[tid + s]; __syncthreads(); }
    if (tid == 0) out[b] = red[0] + pb[0];
}

// ---------------------------------------------------------------------------
extern "C" void kernel_launch(void* const* d_in, const int* in_sizes, int n_in,
                              void* d_out, int out_size, void* d_ws, size_t ws_size,
                              hipStream_t stream)
{
    const float* x_enc = (const float*)d_in[0];
    const int*   isamp = (const int*)d_in[1];
    const float* emb_W = (const float*)d_in[2];
    const float* emb_b = (const float*)d_in[3];
    const float* Wq = (const float*)d_in[4];
    const float* bq = (const float*)d_in[5];
    const float* Wk = (const float*)d_in[6];
    const float* bk = (const float*)d_in[7];
    const float* Wv = (const float*)d_in[8];
    const float* bv = (const float*)d_in[9];
    const float* Wo = (const float*)d_in[10];
    const float* bo = (const float*)d_in[11];
    const float* c1W = (const float*)d_in[12];
    const float* c1b = (const float*)d_in[13];
    const float* c2W = (const float*)d_in[14];
    const float* c2b = (const float*)d_in[15];
    const float* ln1g = (const float*)d_in[16];
    const float* ln1b = (const float*)d_in[17];
    const float* ln2g = (const float*)d_in[18];
    const float* ln2b = (const float*)d_in[19];
    const float* nfg  = (const float*)d_in[20];
    const float* nfb  = (const float*)d_in[21];
    const float* projW = (const float*)d_in[22];
    const float* projb = (const float*)d_in[23];
    (void)d_ws; (void)ws_size; (void)in_sizes; (void)n_in; (void)out_size;

    dim3 blk(256);
    emb_gemm<<<dim3(DM / 64, MROWS / 64), blk, 0, stream>>>(x_enc, emb_W, emb_b);

    for (int l = 0; l < 2; l++) {
        const float* Wq_l = Wq + (size_t)l * DM * HD;
        const float* Wk_l = Wk + (size_t)l * DM * HD;
        const float* Wv_l = Wv + (size_t)l * DM * HD;
        const float* Wo_l = Wo + (size_t)l * HD * DM;

        // all-head Q/K/V: [8192,256] @ [256,2048] x3
        qkv_gemm<<<dim3(HD / 64, MROWS / 64, 3), blk, 0, stream>>>(
            Wq_l, Wk_l, Wv_l, bq + l * HD, bk + l * HD, bv + l * HD);

        sampm_kernel<<<dim3(Bsz * HH * Lseq / 4), blk, 0, stream>>>(isamp);
        topk_kernel<<<dim3(Bsz * HH), blk, 0, stream>>>(0);

        attn_scores<<<dim3(NBT, NCHUNK), blk, 0, stream>>>(0);
        attn_softmax<<<dim3(NBT), blk, 0, stream>>>(0);
        attn_ctx<<<dim3(NBT, NCHUNK), blk, 0, stream>>>(0);

        add_bias_kernel<<<dim3(MROWS), blk, 0, stream>>>(bo + l * DM);
        scatter_kernel<<<dim3(NBT), blk, 0, stream>>>(Wo_l);
        ln_kernel<<<dim3(MROWS / 4), blk, 0, stream>>>(ln1g + l * DM, ln1b + l * DM);

        ffn1_gemm<<<dim3(DFF / 64, MROWS / 64), blk, 0, stream>>>(
            c1W + (size_t)l * DM * DFF, c1b + l * DFF);
        ffn2_gemm<<<dim3(DM / 64, MROWS / 64), blk, 0, stream>>>(
            c2W + (size_t)l * DFF * DM, c2b + l * DM);
        ln_kernel<<<dim3(MROWS / 4), blk, 0, stream>>>(ln2g + l * DM, ln2b + l * DM);
    }

    final_kernel<<<dim3(Bsz), blk, 0, stream>>>(nfg, nfb, projW, projb, (float*)d_out);
}

// Round 7
// 1729.495 us; speedup vs baseline: 2.3939x; 1.0585x over previous
//
#include <hip/hip_runtime.h>
#include <hip/hip_bf16.h>
#include <math.h>

typedef __hip_bfloat16 bf16;

// Problem constants
#define Bsz 4
#define Lseq 2048
#define DM 256       // d_model == per-head D (informer quirk: head dim = d_model)
#define HH 8
#define HD 2048      // H * DM
#define DFF 1024
#define SK 40
#define NTOP 5
#define MROWS 8192   // B * L
#define NBT (Bsz * HH * NTOP)   // 160 (b,h,topquery) triples
#define NCHUNK 8                // key chunks of 256

// ---------------------------------------------------------------------------
// Static device scratch (no d_ws dependence). __align__(256) REQUIRED for the
// float4* casts. Every array fully rewritten before read each call.
__device__ __align__(256) float g_X  [MROWS * DM];    //   8 MB activations
__device__ __align__(256) float g_TMP[MROWS * DM];    //   8 MB residual accum
__device__ __align__(256) float g_Q  [MROWS * HD];    //  64 MB all-head Q
__device__ __align__(256) float g_K  [MROWS * HD];    //  64 MB all-head K
__device__ __align__(256) float g_V  [MROWS * HD];    //  64 MB all-head V
__device__ __align__(256) bf16  g_HF [MROWS * DFF];   //  16 MB FFN hidden (bf16)
__device__ __align__(256) float g_MB [Bsz * HH * Lseq];        // sparsity measure
__device__ __align__(256) float g_SC [NBT * Lseq];             // scores/probs
__device__ __align__(256) float g_CTXP[NBT * NCHUNK * DM];     // partial ctx
__device__ __align__(256) int   g_MTOP[NBT];

__device__ __forceinline__ float ld(const float* p, size_t i) { return p[i]; }
__device__ __forceinline__ float ld(const bf16* p, size_t i) { return __bfloat162float(p[i]); }
__device__ __forceinline__ void st(float* p, size_t i, float v) { p[i] = v; }
__device__ __forceinline__ void st(bf16* p, size_t i, float v) { p[i] = __float2bfloat16(v); }

// ---------------------------------------------------------------------------
// Tiled GEMM: C[.,N] = op(A[.,K] @ W[.,N] + bias (+res))
// 128x64 block tile, BK=16, 8x4 per thread, 256 threads.
// LDS reads are explicit float4 (ds_read_b128): 3 reads (36cyc) per 32
// wave-FMAs (64cyc) -> VALU-bound (round-6 was scalar-read-bound at 73%).
template<typename TA, typename TC, bool GELU, bool RES>
__device__ __forceinline__ void gemm_body(
    const TA* __restrict__ A, const float* __restrict__ W,
    const float* __restrict__ bias, const float* __restrict__ res,
    TC* __restrict__ C, int K, int ldw, int ldc, int bx, int by)
{
    const int BM = 128, BN = 64, BK = 16;
    __shared__ __align__(16) float As[BK][BM + 4];   // row stride 132f=528B (16B-mult)
    __shared__ __align__(16) float Bs[BK][BN];       // row stride 256B
    int tid = threadIdx.x;
    int tx = tid & 15, ty = tid >> 4;                // tx: 4 cols each; ty: 8 rows each
    int row0 = by * BM, col0 = bx * BN;
    float acc[8][4] = {};
    for (int k0 = 0; k0 < K; k0 += BK) {
        #pragma unroll
        for (int i = 0; i < 8; i++) {                // stage A: 128x16
            int idx = tid + i * 256;
            int r = idx >> 4, c = idx & 15;
            As[c][r] = ld(A, (size_t)(row0 + r) * K + k0 + c);
        }
        #pragma unroll
        for (int i = 0; i < 4; i++) {                // stage B: 16x64
            int idx = tid + i * 256;
            int r = idx >> 6, c = idx & 63;
            Bs[r][c] = W[(size_t)(k0 + r) * ldw + col0 + c];
        }
        __syncthreads();
        #pragma unroll
        for (int kk = 0; kk < BK; kk++) {
            float4 b4 = *(const float4*)&Bs[kk][tx * 4];
            float4 a0 = *(const float4*)&As[kk][ty * 8];
            float4 a1 = *(const float4*)&As[kk][ty * 8 + 4];
            float av[8] = {a0.x, a0.y, a0.z, a0.w, a1.x, a1.y, a1.z, a1.w};
            float bv[4] = {b4.x, b4.y, b4.z, b4.w};
            #pragma unroll
            for (int i = 0; i < 8; i++)
                #pragma unroll
                for (int j = 0; j < 4; j++) acc[i][j] += av[i] * bv[j];
        }
        __syncthreads();
    }
    #pragma unroll
    for (int i = 0; i < 8; i++) {
        int r = row0 + ty * 8 + i;
        #pragma unroll
        for (int j = 0; j < 4; j++) {
            int c = col0 + tx * 4 + j;
            float v = acc[i][j] + bias[c];
            if (RES) v += res[(size_t)r * ldc + c];
            if (GELU) v = 0.5f * v * (1.0f + erff(v * 0.70710678118654752440f));
            st(C, (size_t)r * ldc + c, v);
        }
    }
}

// ---- GEMM wrapper kernels ----
__global__ __launch_bounds__(256) void emb_gemm(const float* __restrict__ A,
                                                const float* __restrict__ W,
                                                const float* __restrict__ bias) {
    gemm_body<float, float, false, false>(A, W, bias, nullptr, g_X, 32, DM, DM,
                                          blockIdx.x, blockIdx.y);
}

// All-head Q/K/V per layer: grid (HD/64, MROWS/128, 3); z selects target.
__global__ __launch_bounds__(256) void qkv_gemm(
    const float* __restrict__ Wq, const float* __restrict__ Wk, const float* __restrict__ Wv,
    const float* __restrict__ bq, const float* __restrict__ bk, const float* __restrict__ bv)
{
    int z = blockIdx.z;
    const float* W  = (z == 0) ? Wq : (z == 1) ? Wk : Wv;
    const float* bb = (z == 0) ? bq : (z == 1) ? bk : bv;
    float* C = (z == 0) ? g_Q : (z == 1) ? g_K : g_V;
    gemm_body<float, float, false, false>(g_X, W, bb, nullptr, C, DM, HD, HD,
                                          blockIdx.x, blockIdx.y);
}

__global__ __launch_bounds__(256) void ffn1_gemm(const float* __restrict__ W,
                                                 const float* __restrict__ bias) {
    gemm_body<float, bf16, true, false>(g_X, W, bias, nullptr, g_HF, DM, DFF, DFF,
                                        blockIdx.x, blockIdx.y);
}

__global__ __launch_bounds__(256) void ffn2_gemm(const float* __restrict__ W,
                                                 const float* __restrict__ bias) {
    gemm_body<bf16, float, false, true>(g_HF, W, bias, g_X, g_TMP, DFF, DM, DM,
                                        blockIdx.x, blockIdx.y);
}

// ---------------------------------------------------------------------------
// Sampled scores + sparsity measure M, ALL heads. One wave per (b,h,l).
// Round-7 fix: idx row preloaded into one register/lane + shfl broadcast;
// K-row loads batched 8 deep so memory latency is paid ~5x, not 40x.
__global__ __launch_bounds__(256) void sampm_kernel(const int* __restrict__ idx)
{
    int wid = blockIdx.x * 4 + (threadIdx.x >> 6);   // (b*H+h)*L + l
    int lane = threadIdx.x & 63;
    int l = wid & (Lseq - 1);
    int bh = wid >> 11;
    int b = bh >> 3, h = bh & 7;
    const float4* qrow = (const float4*)(g_Q + ((size_t)(b * Lseq + l)) * HD + h * DM);
    float4 qf = qrow[lane];
    int ui = (lane < SK) ? lane : (SK - 1);          // clamp: idx row has 40 ints
    int iv = idx[l * SK + ui] & (Lseq - 1);
    const float* kbase = g_K + (size_t)b * Lseq * HD + h * DM;
    float maxv = -INFINITY, sumv = 0.f;
    for (int u0 = 0; u0 < SK; u0 += 8) {
        float p[8];
        #pragma unroll
        for (int t = 0; t < 8; t++) {
            int s = __shfl(iv, u0 + t, 64);
            const float4* krow = (const float4*)(kbase + (size_t)s * HD);
            float4 kf = krow[lane];
            p[t] = qf.x * kf.x + qf.y * kf.y + qf.z * kf.z + qf.w * kf.w;
        }
        #pragma unroll
        for (int t = 0; t < 8; t++) {
            float v = p[t];
            #pragma unroll
            for (int off = 32; off > 0; off >>= 1) v += __shfl_down(v, off, 64);
            if (lane == 0) { maxv = fmaxf(maxv, v); sumv += v; }
        }
    }
    if (lane == 0) g_MB[wid] = maxv - sumv * (1.0f / (float)Lseq);
}

// ---------------------------------------------------------------------------
// Top-5 per (b,h): grid 32. 5 masked argmax passes (ties -> lower index).
__global__ __launch_bounds__(256) void topk_kernel(int dummy)
{
    (void)dummy;
    __shared__ float vals[Lseq];
    __shared__ float rv[256];
    __shared__ int ri[256];
    int bh = blockIdx.x, tid = threadIdx.x;
    for (int i = tid; i < Lseq; i += 256) vals[i] = g_MB[bh * Lseq + i];
    __syncthreads();
    for (int t = 0; t < NTOP; t++) {
        float bv = -INFINITY; int bi = Lseq - 1;
        for (int i = tid; i < Lseq; i += 256) {
            float v = vals[i];
            if (v > bv || (v == bv && i < bi)) { bv = v; bi = i; }
        }
        rv[tid] = bv; ri[tid] = bi;
        __syncthreads();
        for (int s = 128; s > 0; s >>= 1) {
            if (tid < s) {
                float ov = rv[tid + s]; int oi = ri[tid + s];
                if (ov > rv[tid] || (ov == rv[tid] && oi < ri[tid])) { rv[tid] = ov; ri[tid] = oi; }
            }
            __syncthreads();
        }
        if (tid == 0) { g_MTOP[bh * NTOP + t] = ri[0]; vals[ri[0] & (Lseq - 1)] = -INFINITY; }
        __syncthreads();
    }
}

// ---------------------------------------------------------------------------
// Scores for top queries: grid (NBT=160, NCHUNK=8). Thread = one key.
__global__ __launch_bounds__(256) void attn_scores(int dummy)
{
    (void)dummy;
    __shared__ __align__(16) float qs[DM];
    int bt = blockIdx.x, chunk = blockIdx.y, tid = threadIdx.x;
    int bh = bt / NTOP;
    int b = bh >> 3, h = bh & 7;
    int l = g_MTOP[bt] & (Lseq - 1);
    qs[tid] = g_Q[((size_t)(b * Lseq + l)) * HD + h * DM + tid];
    __syncthreads();
    int j = chunk * 256 + tid;
    const float4* krow = (const float4*)(g_K + ((size_t)(b * Lseq + j)) * HD + h * DM);
    float acc = 0.f;
    for (int d4 = 0; d4 < DM / 4; d4++) {
        float4 kf = krow[d4];
        float4 qf = ((const float4*)qs)[d4];
        acc += qf.x * kf.x + qf.y * kf.y + qf.z * kf.z + qf.w * kf.w;
    }
    g_SC[(size_t)bt * Lseq + j] = acc;
}

// Softmax in place over g_SC row: grid NBT=160.
__global__ __launch_bounds__(256) void attn_softmax(int dummy)
{
    (void)dummy;
    __shared__ float sc[Lseq];
    __shared__ float red[256];
    int bt = blockIdx.x, tid = threadIdx.x;
    for (int i = tid; i < Lseq; i += 256) sc[i] = g_SC[(size_t)bt * Lseq + i];
    __syncthreads();
    float m = -INFINITY;
    for (int i = tid; i < Lseq; i += 256) m = fmaxf(m, sc[i]);
    red[tid] = m; __syncthreads();
    for (int s = 128; s > 0; s >>= 1) { if (tid < s) red[tid] = fmaxf(red[tid], red[tid + s]); __syncthreads(); }
    m = red[0]; __syncthreads();
    float sum = 0.f;
    for (int i = tid; i < Lseq; i += 256) { float e = expf(sc[i] - m); sc[i] = e; sum += e; }
    red[tid] = sum; __syncthreads();
    for (int s = 128; s > 0; s >>= 1) { if (tid < s) red[tid] += red[tid + s]; __syncthreads(); }
    float inv = 1.0f / red[0]; __syncthreads();
    for (int i = tid; i < Lseq; i += 256) g_SC[(size_t)bt * Lseq + i] = sc[i] * inv;
}

// Partial ctx over one key chunk: grid (NBT=160, NCHUNK=8). Thread = dim.
__global__ __launch_bounds__(256) void attn_ctx(int dummy)
{
    (void)dummy;
    __shared__ float ps[256];
    int bt = blockIdx.x, chunk = blockIdx.y, tid = threadIdx.x;
    int bh = bt / NTOP;
    int b = bh >> 3, h = bh & 7;
    int j0 = chunk * 256;
    ps[tid] = g_SC[(size_t)bt * Lseq + j0 + tid];
    __syncthreads();
    float accv = 0.f;
    const float* vbase = g_V + ((size_t)(b * Lseq + j0)) * HD + h * DM + tid;
    for (int j = 0; j < 256; j++) accv += ps[j] * vbase[(size_t)j * HD];
    g_CTXP[((size_t)bt * NCHUNK + chunk) * DM + tid] = accv;
}

// ---------------------------------------------------------------------------
// g_TMP = g_X + bo (broadcast)
__global__ __launch_bounds__(256) void add_bias_kernel(const float* __restrict__ bo)
{
    int i = blockIdx.x * 256 + threadIdx.x;
    g_TMP[i] = g_X[i] + bo[i & (DM - 1)];
}

// Reduce ctx partials, project through Wo_h, scatter-add: grid NBT=160.
__global__ __launch_bounds__(256) void scatter_kernel(const float* __restrict__ Wo_l)
{
    __shared__ float cs[DM];
    int bt = blockIdx.x, tid = threadIdx.x;
    int bh = bt / NTOP;
    int b = bh >> 3, h = bh & 7;
    float s = 0.f;
    #pragma unroll
    for (int c = 0; c < NCHUNK; c++) s += g_CTXP[((size_t)bt * NCHUNK + c) * DM + tid];
    cs[tid] = s;
    __syncthreads();
    int row = g_MTOP[bt] & (Lseq - 1);
    float acc = 0.f;
    const float* w = Wo_l + (size_t)h * DM * DM + tid;
    for (int d = 0; d < DM; d++) acc += cs[d] * w[(size_t)d * DM];
    atomicAdd(&g_TMP[((size_t)(b * Lseq) + row) * DM + tid], acc);
}

// ---------------------------------------------------------------------------
// LayerNorm g_TMP -> g_X, one wave per row of 256
__global__ __launch_bounds__(256) void ln_kernel(const float* __restrict__ g,
                                                 const float* __restrict__ bb)
{
    int wid = blockIdx.x * 4 + (threadIdx.x >> 6);
    if (wid >= MROWS) return;
    int lane = threadIdx.x & 63;
    const float4* row = (const float4*)(g_TMP + (size_t)wid * DM);
    float4 v = row[lane];
    float s = v.x + v.y + v.z + v.w;
    #pragma unroll
    for (int off = 32; off > 0; off >>= 1) s += __shfl_down(s, off, 64);
    s = __shfl(s, 0, 64);
    float mean = s * (1.f / DM);
    float4 d = {v.x - mean, v.y - mean, v.z - mean, v.w - mean};
    float q = d.x * d.x + d.y * d.y + d.z * d.z + d.w * d.w;
    #pragma unroll
    for (int off = 32; off > 0; off >>= 1) q += __shfl_down(q, off, 64);
    q = __shfl(q, 0, 64);
    float inv = rsqrtf(q * (1.f / DM) + 1e-5f);
    int c = lane * 4;
    float4 o;
    o.x = d.x * inv * g[c + 0] + bb[c + 0];
    o.y = d.y * inv * g[c + 1] + bb[c + 1];
    o.z = d.z * inv * g[c + 2] + bb[c + 2];
    o.w = d.w * inv * g[c + 3] + bb[c + 3];
    ((float4*)(g_X + (size_t)wid * DM))[lane] = o;
}

// ---------------------------------------------------------------------------
// Final: LN(nf) on row L-1 of each batch, dot with proj_W, + proj_b -> out[b]
__global__ __launch_bounds__(256) void final_kernel(
    const float* __restrict__ g, const float* __restrict__ bb,
    const float* __restrict__ pw, const float* __restrict__ pb,
    float* __restrict__ out)
{
    __shared__ float red[256];
    int b = blockIdx.x, tid = threadIdx.x;
    const float* row = g_X + ((size_t)(b * Lseq + Lseq - 1)) * DM;
    float v = row[tid];
    red[tid] = v; __syncthreads();
    for (int s = 128; s > 0; s >>= 1) { if (tid < s) red[tid] += red[tid + s]; __syncthreads(); }
    float mean = red[0] * (1.f / DM); __syncthreads();
    float d = v - mean;
    red[tid] = d * d; __syncthreads();
    for (int s = 128; s > 0; s >>= 1) { if (tid < s) red[tid] += red[tid + s]; __syncthreads(); }
    float var = red[0] * (1.f / DM); __syncthreads();
    float xn = d * rsqrtf(var + 1e-5f) * g[tid] + bb[tid];
    red[tid] = xn * pw[tid]; __syncthreads();
    for (int s = 128; s > 0; s >>= 1) { if (tid < s) red[tid] += red[tid + s]; __syncthreads(); }
    if (tid == 0) out[b] = red[0] + pb[0];
}

// ---------------------------------------------------------------------------
extern "C" void kernel_launch(void* const* d_in, const int* in_sizes, int n_in,
                              void* d_out, int out_size, void* d_ws, size_t ws_size,
                              hipStream_t stream)
{
    const float* x_enc = (const float*)d_in[0];
    const int*   isamp = (const int*)d_in[1];
    const float* emb_W = (const float*)d_in[2];
    const float* emb_b = (const float*)d_in[3];
    const float* Wq = (const float*)d_in[4];
    const float* bq = (const float*)d_in[5];
    const float* Wk = (const float*)d_in[6];
    const float* bk = (const float*)d_in[7];
    const float* Wv = (const float*)d_in[8];
    const float* bv = (const float*)d_in[9];
    const float* Wo = (const float*)d_in[10];
    const float* bo = (const float*)d_in[11];
    const float* c1W = (const float*)d_in[12];
    const float* c1b = (const float*)d_in[13];
    const float* c2W = (const float*)d_in[14];
    const float* c2b = (const float*)d_in[15];
    const float* ln1g = (const float*)d_in[16];
    const float* ln1b = (const float*)d_in[17];
    const float* ln2g = (const float*)d_in[18];
    const float* ln2b = (const float*)d_in[19];
    const float* nfg  = (const float*)d_in[20];
    const float* nfb  = (const float*)d_in[21];
    const float* projW = (const float*)d_in[22];
    const float* projb = (const float*)d_in[23];
    (void)d_ws; (void)ws_size; (void)in_sizes; (void)n_in; (void)out_size;

    dim3 blk(256);
    emb_gemm<<<dim3(DM / 64, MROWS / 128), blk, 0, stream>>>(x_enc, emb_W, emb_b);

    for (int l = 0; l < 2; l++) {
        const float* Wq_l = Wq + (size_t)l * DM * HD;
        const float* Wk_l = Wk + (size_t)l * DM * HD;
        const float* Wv_l = Wv + (size_t)l * DM * HD;
        const float* Wo_l = Wo + (size_t)l * HD * DM;

        qkv_gemm<<<dim3(HD / 64, MROWS / 128, 3), blk, 0, stream>>>(
            Wq_l, Wk_l, Wv_l, bq + l * HD, bk + l * HD, bv + l * HD);

        sampm_kernel<<<dim3(Bsz * HH * Lseq / 4), blk, 0, stream>>>(isamp);
        topk_kernel<<<dim3(Bsz * HH), blk, 0, stream>>>(0);

        attn_scores<<<dim3(NBT, NCHUNK), blk, 0, stream>>>(0);
        attn_softmax<<<dim3(NBT), blk, 0, stream>>>(0);
        attn_ctx<<<dim3(NBT, NCHUNK), blk, 0, stream>>>(0);

        add_bias_kernel<<<dim3(MROWS), blk, 0, stream>>>(bo + l * DM);
        scatter_kernel<<<dim3(NBT), blk, 0, stream>>>(Wo_l);
        ln_kernel<<<dim3(MROWS / 4), blk, 0, stream>>>(ln1g + l * DM, ln1b + l * DM);

        ffn1_gemm<<<dim3(DFF / 64, MROWS / 128), blk, 0, stream>>>(
            c1W + (size_t)l * DM * DFF, c1b + l * DFF);
        ffn2_gemm<<<dim3(DM / 64, MROWS / 128), blk, 0, stream>>>(
            c2W + (size_t)l * DFF * DM, c2b + l * DM);
        ln_kernel<<<dim3(MROWS / 4), blk, 0, stream>>>(ln2g + l * DM, ln2b + l * DM);
    }

    final_kernel<<<dim3(Bsz), blk, 0, stream>>>(nfg, nfb, projW, projb, (float*)d_out);
}

// Round 8
// 1656.137 us; speedup vs baseline: 2.5000x; 1.0443x over previous
//
#include <hip/hip_runtime.h>
#include <hip/hip_bf16.h>
#include <math.h>

typedef __hip_bfloat16 bf16;
typedef __attribute__((ext_vector_type(8))) short bf16x8;   // MFMA A/B frag (8 bf16)
typedef __attribute__((ext_vector_type(4))) float f32x4;    // MFMA C/D frag

// Problem constants
#define Bsz 4
#define Lseq 2048
#define DM 256       // d_model == per-head D
#define HH 8
#define HD 2048      // H * DM
#define DFF 1024
#define SK 40
#define NTOP 5
#define MROWS 8192   // B * L
#define NBT (Bsz * HH * NTOP)   // 160
#define NCHUNK 8

// ---------------------------------------------------------------------------
// Static device scratch. __align__(256) REQUIRED (float4 casts).
__device__ __align__(256) float g_X  [MROWS * DM];    //   8 MB activations
__device__ __align__(256) float g_TMP[MROWS * DM];    //   8 MB residual accum
__device__ __align__(256) float g_Q  [MROWS * HD];    //  64 MB all-head Q (fp32: selection path)
__device__ __align__(256) float g_K  [MROWS * HD];    //  64 MB all-head K (fp32: selection path)
__device__ __align__(256) float g_V  [MROWS * HD];    //  64 MB all-head V
__device__ __align__(256) float g_HF [MROWS * DFF];   //  32 MB FFN hidden
__device__ __align__(256) float g_MB [Bsz * HH * Lseq];
__device__ __align__(256) float g_SC [NBT * Lseq];
__device__ __align__(256) float g_CTXP[NBT * NCHUNK * DM];
__device__ __align__(256) int   g_MTOP[NBT];

__device__ __forceinline__ float ld(const float* p, size_t i) { return p[i]; }
__device__ __forceinline__ float ld(const bf16* p, size_t i) { return __bfloat162float(p[i]); }
__device__ __forceinline__ void st(float* p, size_t i, float v) { p[i] = v; }
__device__ __forceinline__ void st(bf16* p, size_t i, float v) { p[i] = __float2bfloat16(v); }
__device__ __forceinline__ short f2bf(float v) {
    union { bf16 h; short s; } u; u.h = __float2bfloat16(v); return u.s;
}

// ---------------------------------------------------------------------------
// fp32 tiled GEMM (kept for embedding + Q/K — selection path must stay
// bit-identical to the passing round-7 config). 128x64, BK=16, 8x4/thread.
template<typename TA, typename TC, bool GELU, bool RES>
__device__ __forceinline__ void gemm_body(
    const TA* __restrict__ A, const float* __restrict__ W,
    const float* __restrict__ bias, const float* __restrict__ res,
    TC* __restrict__ C, int K, int ldw, int ldc, int bx, int by)
{
    const int BM = 128, BN = 64, BK = 16;
    __shared__ __align__(16) float As[BK][BM + 4];
    __shared__ __align__(16) float Bs[BK][BN];
    int tid = threadIdx.x;
    int tx = tid & 15, ty = tid >> 4;
    int row0 = by * BM, col0 = bx * BN;
    float acc[8][4] = {};
    for (int k0 = 0; k0 < K; k0 += BK) {
        #pragma unroll
        for (int i = 0; i < 8; i++) {
            int idx = tid + i * 256;
            int r = idx >> 4, c = idx & 15;
            As[c][r] = ld(A, (size_t)(row0 + r) * K + k0 + c);
        }
        #pragma unroll
        for (int i = 0; i < 4; i++) {
            int idx = tid + i * 256;
            int r = idx >> 6, c = idx & 63;
            Bs[r][c] = W[(size_t)(k0 + r) * ldw + col0 + c];
        }
        __syncthreads();
        #pragma unroll
        for (int kk = 0; kk < BK; kk++) {
            float4 b4 = *(const float4*)&Bs[kk][tx * 4];
            float4 a0 = *(const float4*)&As[kk][ty * 8];
            float4 a1 = *(const float4*)&As[kk][ty * 8 + 4];
            float av[8] = {a0.x, a0.y, a0.z, a0.w, a1.x, a1.y, a1.z, a1.w};
            float bv[4] = {b4.x, b4.y, b4.z, b4.w};
            #pragma unroll
            for (int i = 0; i < 8; i++)
                #pragma unroll
                for (int j = 0; j < 4; j++) acc[i][j] += av[i] * bv[j];
        }
        __syncthreads();
    }
    #pragma unroll
    for (int i = 0; i < 8; i++) {
        int r = row0 + ty * 8 + i;
        #pragma unroll
        for (int j = 0; j < 4; j++) {
            int c = col0 + tx * 4 + j;
            float v = acc[i][j] + bias[c];
            if (RES) v += res[(size_t)r * ldc + c];
            if (GELU) v = 0.5f * v * (1.0f + erff(v * 0.70710678118654752440f));
            st(C, (size_t)r * ldc + c, v);
        }
    }
}

__global__ __launch_bounds__(256) void emb_gemm(const float* __restrict__ A,
                                                const float* __restrict__ W,
                                                const float* __restrict__ bias) {
    gemm_body<float, float, false, false>(A, W, bias, nullptr, g_X, 32, DM, DM,
                                          blockIdx.x, blockIdx.y);
}

// Q and K only (z in {0,1}) — fp32, identical math to round 7.
__global__ __launch_bounds__(256) void qk_gemm(
    const float* __restrict__ Wq, const float* __restrict__ Wk,
    const float* __restrict__ bq, const float* __restrict__ bk)
{
    int z = blockIdx.z;
    const float* W  = z ? Wk : Wq;
    const float* bb = z ? bk : bq;
    float* C = z ? g_K : g_Q;
    gemm_body<float, float, false, false>(g_X, W, bb, nullptr, C, DM, HD, HD,
                                          blockIdx.x, blockIdx.y);
}

// ---------------------------------------------------------------------------
// bf16 MFMA GEMM: C[.,N] = op(A @ W + bias). A,W fp32 global, converted to
// bf16 during LDS staging; fp32 accumulation in AGPRs.
// 128x128 tile, BK=32, 4 waves (2x2 of 64x64), mfma_f32_16x16x32_bf16.
// Frag layouts (m89/m91/m120-verified): A[m=lane&15][k=quad*8+j],
// B[k=quad*8+j][n=lane&15], C/D col=lane&15 row=quad*4+reg.
template<typename TC, bool GELU, bool RES>
__device__ __forceinline__ void mf_gemm_body(
    const float* __restrict__ A, const float* __restrict__ W,
    const float* __restrict__ bias, const float* __restrict__ res,
    TC* __restrict__ C, int K, int ldw, int ldc, int bx, int by)
{
    __shared__ __align__(16) short As[128][40];   // [m][k], stride 40 (80B: 16B-mult, 2-way banks)
    __shared__ __align__(16) short Bs[128][40];   // [n][k]
    int tid = threadIdx.x;
    int wid = tid >> 6, lane = tid & 63;
    int wm = wid >> 1, wn = wid & 1;
    int quad = lane >> 4, l16 = lane & 15;
    int row0 = by * 128, col0 = bx * 128;
    f32x4 acc[4][4] = {};
    for (int k0 = 0; k0 < K; k0 += 32) {
        // stage A: 128 rows x 32 k. thread -> (r = tid>>3 + i*32, c = (tid&7)*4)
        int ar = tid >> 3, ac = (tid & 7) * 4;
        #pragma unroll
        for (int i = 0; i < 4; i++) {
            float4 v = *(const float4*)&A[(size_t)(row0 + ar + i * 32) * K + k0 + ac];
            short4 s4 = {f2bf(v.x), f2bf(v.y), f2bf(v.z), f2bf(v.w)};
            *(short4*)&As[ar + i * 32][ac] = s4;
        }
        // stage B (transposed): 32 k x 128 n. thread -> (k = tid>>5 + i*8, n = (tid&31)*4)
        int bk = tid >> 5, bn = (tid & 31) * 4;
        #pragma unroll
        for (int i = 0; i < 4; i++) {
            int kk = bk + i * 8;
            float4 v = *(const float4*)&W[(size_t)(k0 + kk) * ldw + col0 + bn];
            Bs[bn + 0][kk] = f2bf(v.x);
            Bs[bn + 1][kk] = f2bf(v.y);
            Bs[bn + 2][kk] = f2bf(v.z);
            Bs[bn + 3][kk] = f2bf(v.w);
        }
        __syncthreads();
        bf16x8 af[4], bf_[4];
        #pragma unroll
        for (int mt = 0; mt < 4; mt++)
            af[mt] = *(const bf16x8*)&As[wm * 64 + mt * 16 + l16][quad * 8];
        #pragma unroll
        for (int nt = 0; nt < 4; nt++)
            bf_[nt] = *(const bf16x8*)&Bs[wn * 64 + nt * 16 + l16][quad * 8];
        #pragma unroll
        for (int mt = 0; mt < 4; mt++)
            #pragma unroll
            for (int nt = 0; nt < 4; nt++)
                acc[mt][nt] = __builtin_amdgcn_mfma_f32_16x16x32_bf16(
                    af[mt], bf_[nt], acc[mt][nt], 0, 0, 0);
        __syncthreads();
    }
    #pragma unroll
    for (int mt = 0; mt < 4; mt++) {
        #pragma unroll
        for (int nt = 0; nt < 4; nt++) {
            int col = col0 + wn * 64 + nt * 16 + l16;
            float bv = bias[col];
            #pragma unroll
            for (int r = 0; r < 4; r++) {
                int row = row0 + wm * 64 + mt * 16 + quad * 4 + r;
                float v = acc[mt][nt][r] + bv;
                if (RES) v += res[(size_t)row * ldc + col];
                if (GELU) v = 0.5f * v * (1.0f + erff(v * 0.70710678118654752440f));
                st(C, (size_t)row * ldc + col, v);
            }
        }
    }
}

// V projection: [8192,256] @ [256,2048] -> g_V
__global__ __launch_bounds__(256) void v_mf(const float* __restrict__ W,
                                            const float* __restrict__ bias) {
    mf_gemm_body<float, false, false>(g_X, W, bias, nullptr, g_V, DM, HD, HD,
                                      blockIdx.x, blockIdx.y);
}
// FFN1: g_HF = gelu(g_X @ c1W + c1b)
__global__ __launch_bounds__(256) void ffn1_mf(const float* __restrict__ W,
                                               const float* __restrict__ bias) {
    mf_gemm_body<float, true, false>(g_X, W, bias, nullptr, g_HF, DM, DFF, DFF,
                                     blockIdx.x, blockIdx.y);
}
// FFN2: g_TMP = g_HF @ c2W + c2b + g_X
__global__ __launch_bounds__(256) void ffn2_mf(const float* __restrict__ W,
                                               const float* __restrict__ bias) {
    mf_gemm_body<float, false, true>(g_HF, W, bias, g_X, g_TMP, DFF, DM, DM,
                                     blockIdx.x, blockIdx.y);
}

// ---------------------------------------------------------------------------
// Sampled scores + sparsity M, all heads. One wave per (b,h,l).
// Round-8: lane = (sample-group sg: 2b) x (dim-block dl: 16 lanes x 16 dims);
// 4 samples/round, 4 shfl_xor per round (was 6 shfls x 8) -> DS-pipe ~5x lighter.
__global__ __launch_bounds__(256) void sampm_kernel(const int* __restrict__ idx)
{
    int wid = blockIdx.x * 4 + (threadIdx.x >> 6);   // (b*H+h)*L + l
    int lane = threadIdx.x & 63;
    int l = wid & (Lseq - 1);
    int bh = wid >> 11;
    int b = bh >> 3, h = bh & 7;
    int sg = lane >> 4, dl = lane & 15;
    const float4* qrow = (const float4*)(g_Q + ((size_t)(b * Lseq + l)) * HD + h * DM);
    float4 q0 = qrow[dl * 4 + 0], q1 = qrow[dl * 4 + 1];
    float4 q2 = qrow[dl * 4 + 2], q3 = qrow[dl * 4 + 3];
    int ui = (lane < SK) ? lane : (SK - 1);
    int iv = idx[l * SK + ui] & (Lseq - 1);
    const float* kbase = g_K + (size_t)b * Lseq * HD + h * DM;
    float maxv = -INFINITY, sumv = 0.f;
    #pragma unroll
    for (int r = 0; r < SK / 4; r++) {
        int s = __shfl(iv, r * 4 + sg, 64);
        const float4* krow = (const float4*)(kbase + (size_t)s * HD);
        float4 k0 = krow[dl * 4 + 0], k1 = krow[dl * 4 + 1];
        float4 k2 = krow[dl * 4 + 2], k3 = krow[dl * 4 + 3];
        float p = q0.x * k0.x + q0.y * k0.y + q0.z * k0.z + q0.w * k0.w
                + q1.x * k1.x + q1.y * k1.y + q1.z * k1.z + q1.w * k1.w
                + q2.x * k2.x + q2.y * k2.y + q2.z * k2.z + q2.w * k2.w
                + q3.x * k3.x + q3.y * k3.y + q3.z * k3.z + q3.w * k3.w;
        p += __shfl_xor(p, 1, 64);
        p += __shfl_xor(p, 2, 64);
        p += __shfl_xor(p, 4, 64);
        p += __shfl_xor(p, 8, 64);   // all 16 lanes of sg-group now hold the dot
        maxv = fmaxf(maxv, p); sumv += p;
    }
    maxv = fmaxf(maxv, __shfl_xor(maxv, 16, 64));
    maxv = fmaxf(maxv, __shfl_xor(maxv, 32, 64));
    sumv += __shfl_xor(sumv, 16, 64);
    sumv += __shfl_xor(sumv, 32, 64);
    if (lane == 0) g_MB[wid] = maxv - sumv * (1.0f / (float)Lseq);
}

// ---------------------------------------------------------------------------
// Top-5 per (b,h): grid 32. 5 masked argmax passes (ties -> lower index).
__global__ __launch_bounds__(256) void topk_kernel(int dummy)
{
    (void)dummy;
    __shared__ float vals[Lseq];
    __shared__ float rv[256];
    __shared__ int ri[256];
    int bh = blockIdx.x, tid = threadIdx.x;
    for (int i = tid; i < Lseq; i += 256) vals[i] = g_MB[bh * Lseq + i];
    __syncthreads();
    for (int t = 0; t < NTOP; t++) {
        float bv = -INFINITY; int bi = Lseq - 1;
        for (int i = tid; i < Lseq; i += 256) {
            float v = vals[i];
            if (v > bv || (v == bv && i < bi)) { bv = v; bi = i; }
        }
        rv[tid] = bv; ri[tid] = bi;
        __syncthreads();
        for (int s = 128; s > 0; s >>= 1) {
            if (tid < s) {
                float ov = rv[tid + s]; int oi = ri[tid + s];
                if (ov > rv[tid] || (ov == rv[tid] && oi < ri[tid])) { rv[tid] = ov; ri[tid] = oi; }
            }
            __syncthreads();
        }
        if (tid == 0) { g_MTOP[bh * NTOP + t] = ri[0]; vals[ri[0] & (Lseq - 1)] = -INFINITY; }
        __syncthreads();
    }
}

// ---------------------------------------------------------------------------
// Scores for top queries: grid (NBT, NCHUNK). Thread = one key.
__global__ __launch_bounds__(256) void attn_scores(int dummy)
{
    (void)dummy;
    __shared__ __align__(16) float qs[DM];
    int bt = blockIdx.x, chunk = blockIdx.y, tid = threadIdx.x;
    int bh = bt / NTOP;
    int b = bh >> 3, h = bh & 7;
    int l = g_MTOP[bt] & (Lseq - 1);
    qs[tid] = g_Q[((size_t)(b * Lseq + l)) * HD + h * DM + tid];
    __syncthreads();
    int j = chunk * 256 + tid;
    const float4* krow = (const float4*)(g_K + ((size_t)(b * Lseq + j)) * HD + h * DM);
    float acc = 0.f;
    for (int d4 = 0; d4 < DM / 4; d4++) {
        float4 kf = krow[d4];
        float4 qf = ((const float4*)qs)[d4];
        acc += qf.x * kf.x + qf.y * kf.y + qf.z * kf.z + qf.w * kf.w;
    }
    g_SC[(size_t)bt * Lseq + j] = acc;
}

// Softmax in place over g_SC row: grid NBT.
__global__ __launch_bounds__(256) void attn_softmax(int dummy)
{
    (void)dummy;
    __shared__ float sc[Lseq];
    __shared__ float red[256];
    int bt = blockIdx.x, tid = threadIdx.x;
    for (int i = tid; i < Lseq; i += 256) sc[i] = g_SC[(size_t)bt * Lseq + i];
    __syncthreads();
    float m = -INFINITY;
    for (int i = tid; i < Lseq; i += 256) m = fmaxf(m, sc[i]);
    red[tid] = m; __syncthreads();
    for (int s = 128; s > 0; s >>= 1) { if (tid < s) red[tid] = fmaxf(red[tid], red[tid + s]); __syncthreads(); }
    m = red[0]; __syncthreads();
    float sum = 0.f;
    for (int i = tid; i < Lseq; i += 256) { float e = expf(sc[i] - m); sc[i] = e; sum += e; }
    red[tid] = sum; __syncthreads();
    for (int s = 128; s > 0; s >>= 1) { if (tid < s) red[tid] += red[tid + s]; __syncthreads(); }
    float inv = 1.0f / red[0]; __syncthreads();
    for (int i = tid; i < Lseq; i += 256) g_SC[(size_t)bt * Lseq + i] = sc[i] * inv;
}

// Partial ctx over one key chunk: grid (NBT, NCHUNK). Thread = dim.
__global__ __launch_bounds__(256) void attn_ctx(int dummy)
{
    (void)dummy;
    __shared__ float ps[256];
    int bt = blockIdx.x, chunk = blockIdx.y, tid = threadIdx.x;
    int bh = bt / NTOP;
    int b = bh >> 3, h = bh & 7;
    int j0 = chunk * 256;
    ps[tid] = g_SC[(size_t)bt * Lseq + j0 + tid];
    __syncthreads();
    float accv = 0.f;
    const float* vbase = g_V + ((size_t)(b * Lseq + j0)) * HD + h * DM + tid;
    for (int j = 0; j < 256; j++) accv += ps[j] * vbase[(size_t)j * HD];
    g_CTXP[((size_t)bt * NCHUNK + chunk) * DM + tid] = accv;
}

// ---------------------------------------------------------------------------
// g_TMP = g_X + bo (broadcast)
__global__ __launch_bounds__(256) void add_bias_kernel(const float* __restrict__ bo)
{
    int i = blockIdx.x * 256 + threadIdx.x;
    g_TMP[i] = g_X[i] + bo[i & (DM - 1)];
}

// Reduce ctx partials, project through Wo_h, scatter-add: grid NBT.
__global__ __launch_bounds__(256) void scatter_kernel(const float* __restrict__ Wo_l)
{
    __shared__ float cs[DM];
    int bt = blockIdx.x, tid = threadIdx.x;
    int bh = bt / NTOP;
    int b = bh >> 3, h = bh & 7;
    float s = 0.f;
    #pragma unroll
    for (int c = 0; c < NCHUNK; c++) s += g_CTXP[((size_t)bt * NCHUNK + c) * DM + tid];
    cs[tid] = s;
    __syncthreads();
    int row = g_MTOP[bt] & (Lseq - 1);
    float acc = 0.f;
    const float* w = Wo_l + (size_t)h * DM * DM + tid;
    for (int d = 0; d < DM; d++) acc += cs[d] * w[(size_t)d * DM];
    atomicAdd(&g_TMP[((size_t)(b * Lseq) + row) * DM + tid], acc);
}

// ---------------------------------------------------------------------------
// LayerNorm g_TMP -> g_X, one wave per row of 256
__global__ __launch_bounds__(256) void ln_kernel(const float* __restrict__ g,
                                                 const float* __restrict__ bb)
{
    int wid = blockIdx.x * 4 + (threadIdx.x >> 6);
    if (wid >= MROWS) return;
    int lane = threadIdx.x & 63;
    const float4* row = (const float4*)(g_TMP + (size_t)wid * DM);
    float4 v = row[lane];
    float s = v.x + v.y + v.z + v.w;
    #pragma unroll
    for (int off = 32; off > 0; off >>= 1) s += __shfl_down(s, off, 64);
    s = __shfl(s, 0, 64);
    float mean = s * (1.f / DM);
    float4 d = {v.x - mean, v.y - mean, v.z - mean, v.w - mean};
    float q = d.x * d.x + d.y * d.y + d.z * d.z + d.w * d.w;
    #pragma unroll
    for (int off = 32; off > 0; off >>= 1) q += __shfl_down(q, off, 64);
    q = __shfl(q, 0, 64);
    float inv = rsqrtf(q * (1.f / DM) + 1e-5f);
    int c = lane * 4;
    float4 o;
    o.x = d.x * inv * g[c + 0] + bb[c + 0];
    o.y = d.y * inv * g[c + 1] + bb[c + 1];
    o.z = d.z * inv * g[c + 2] + bb[c + 2];
    o.w = d.w * inv * g[c + 3] + bb[c + 3];
    ((float4*)(g_X + (size_t)wid * DM))[lane] = o;
}

// ---------------------------------------------------------------------------
// Final: LN(nf) on row L-1 of each batch, dot with proj_W, + proj_b -> out[b]
__global__ __launch_bounds__(256) void final_kernel(
    const float* __restrict__ g, const float* __restrict__ bb,
    const float* __restrict__ pw, const float* __restrict__ pb,
    float* __restrict__ out)
{
    __shared__ float red[256];
    int b = blockIdx.x, tid = threadIdx.x;
    const float* row = g_X + ((size_t)(b * Lseq + Lseq - 1)) * DM;
    float v = row[tid];
    red[tid] = v; __syncthreads();
    for (int s = 128; s > 0; s >>= 1) { if (tid < s) red[tid] += red[tid + s]; __syncthreads(); }
    float mean = red[0] * (1.f / DM); __syncthreads();
    float d = v - mean;
    red[tid] = d * d; __syncthreads();
    for (int s = 128; s > 0; s >>= 1) { if (tid < s) red[tid] += red[tid + s]; __syncthreads(); }
    float var = red[0] * (1.f / DM); __syncthreads();
    float xn = d * rsqrtf(var + 1e-5f) * g[tid] + bb[tid];
    red[tid] = xn * pw[tid]; __syncthreads();
    for (int s = 128; s > 0; s >>= 1) { if (tid < s) red[tid] += red[tid + s]; __syncthreads(); }
    if (tid == 0) out[b] = red[0] + pb[0];
}

// ---------------------------------------------------------------------------
extern "C" void kernel_launch(void* const* d_in, const int* in_sizes, int n_in,
                              void* d_out, int out_size, void* d_ws, size_t ws_size,
                              hipStream_t stream)
{
    const float* x_enc = (const float*)d_in[0];
    const int*   isamp = (const int*)d_in[1];
    const float* emb_W = (const float*)d_in[2];
    const float* emb_b = (const float*)d_in[3];
    const float* Wq = (const float*)d_in[4];
    const float* bq = (const float*)d_in[5];
    const float* Wk = (const float*)d_in[6];
    const float* bk = (const float*)d_in[7];
    const float* Wv = (const float*)d_in[8];
    const float* bv = (const float*)d_in[9];
    const float* Wo = (const float*)d_in[10];
    const float* bo = (const float*)d_in[11];
    const float* c1W = (const float*)d_in[12];
    const float* c1b = (const float*)d_in[13];
    const float* c2W = (const float*)d_in[14];
    const float* c2b = (const float*)d_in[15];
    const float* ln1g = (const float*)d_in[16];
    const float* ln1b = (const float*)d_in[17];
    const float* ln2g = (const float*)d_in[18];
    const float* ln2b = (const float*)d_in[19];
    const float* nfg  = (const float*)d_in[20];
    const float* nfb  = (const float*)d_in[21];
    const float* projW = (const float*)d_in[22];
    const float* projb = (const float*)d_in[23];
    (void)d_ws; (void)ws_size; (void)in_sizes; (void)n_in; (void)out_size;

    dim3 blk(256);
    emb_gemm<<<dim3(DM / 64, MROWS / 128), blk, 0, stream>>>(x_enc, emb_W, emb_b);

    for (int l = 0; l < 2; l++) {
        const float* Wq_l = Wq + (size_t)l * DM * HD;
        const float* Wk_l = Wk + (size_t)l * DM * HD;
        const float* Wv_l = Wv + (size_t)l * DM * HD;
        const float* Wo_l = Wo + (size_t)l * HD * DM;

        qk_gemm<<<dim3(HD / 64, MROWS / 128, 2), blk, 0, stream>>>(
            Wq_l, Wk_l, bq + l * HD, bk + l * HD);
        v_mf<<<dim3(HD / 128, MROWS / 128), blk, 0, stream>>>(Wv_l, bv + l * HD);

        sampm_kernel<<<dim3(Bsz * HH * Lseq / 4), blk, 0, stream>>>(isamp);
        topk_kernel<<<dim3(Bsz * HH), blk, 0, stream>>>(0);

        attn_scores<<<dim3(NBT, NCHUNK), blk, 0, stream>>>(0);
        attn_softmax<<<dim3(NBT), blk, 0, stream>>>(0);
        attn_ctx<<<dim3(NBT, NCHUNK), blk, 0, stream>>>(0);

        add_bias_kernel<<<dim3(MROWS), blk, 0, stream>>>(bo + l * DM);
        scatter_kernel<<<dim3(NBT), blk, 0, stream>>>(Wo_l);
        ln_kernel<<<dim3(MROWS / 4), blk, 0, stream>>>(ln1g + l * DM, ln1b + l * DM);

        ffn1_mf<<<dim3(DFF / 128, MROWS / 128), blk, 0, stream>>>(
            c1W + (size_t)l * DM * DFF, c1b + l * DFF);
        ffn2_mf<<<dim3(DM / 128, MROWS / 128), blk, 0, stream>>>(
            c2W + (size_t)l * DFF * DM, c2b + l * DM);
        ln_kernel<<<dim3(MROWS / 4), blk, 0, stream>>>(ln2g + l * DM, ln2b + l * DM);
    }

    final_kernel<<<dim3(Bsz), blk, 0, stream>>>(nfg, nfb, projW, projb, (float*)d_out);
}